// Round 12
// baseline (181.171 us; speedup 1.0000x reference)
//
#include <hip/hip_runtime.h>

typedef unsigned short ushort_t;
typedef __attribute__((ext_vector_type(8))) short short8;
typedef __attribute__((ext_vector_type(4))) float f32x4;

#define DIMC 512
#define PN   32768                  // 8*64*64 spatial positions
#define SQRTC 22.627416997969522f   // sqrt(512)

__device__ __forceinline__ ushort_t f2bf(float f) {
  unsigned int u = __float_as_uint(f);
  unsigned int r = u + 0x7fffu + ((u >> 16) & 1u);   // round-to-nearest-even
  return (ushort_t)(r >> 16);
}

// swizzle key: spreads 8 values over 16 consecutive rows AND over stride-4 rows
__device__ __forceinline__ int kkey(int r) { return (r & 7) ^ ((r >> 2) & 7); }

__device__ __forceinline__ uint4 pack8(float4 a, float4 b) {
  union { ushort_t u[8]; uint4 v; } r;
  r.u[0] = f2bf(a.x); r.u[1] = f2bf(a.y); r.u[2] = f2bf(a.z); r.u[3] = f2bf(a.w);
  r.u[4] = f2bf(b.x); r.u[5] = f2bf(b.y); r.u[6] = f2bf(b.z); r.u[7] = f2bf(b.w);
  return r.v;
}

// ---------------- weight GEMM with fused cast+transpose staging + fb (2-in-1):
// blocks 0..15:   Mp2(frag layout) = (wproj @ Wv^T) * gamma
// blocks 16..143: fb[o] = wproj[o,:]·bqkv[1024:1536] + bproj[o]
// Mp2 layout: idx(o,c) = ((((w*8+kb)*2+ks)*4+mi)*64 + q*16+ln)*8 + j
//   w=o>>6, mi=(o>>4)&3, ln=o&15, kb=c>>6, ks=(c>>5)&1, q=(c>>3)&3, j=c&7
__global__ __launch_bounds__(256) void k_wgemm(
    const float* __restrict__ wproj,
    const float* __restrict__ wqkv,
    const float* __restrict__ bqkv,
    const float* __restrict__ bproj,
    const float* __restrict__ gamma,
    ushort_t* __restrict__ Mp2,
    float* __restrict__ fb) {
  int bid = blockIdx.x, tid = threadIdx.x;
  if (bid >= 16) {
    int wave = tid >> 6, lane = tid & 63;
    int o = (bid - 16) * 4 + wave;          // 128 blocks -> o in [0,512)
    float part = 0.f;
#pragma unroll
    for (int i = 0; i < 8; ++i) {
      int k = lane + i * 64;
      part += wproj[o * DIMC + k] * bqkv[1024 + k];
    }
    for (int off = 32; off; off >>= 1) part += __shfl_down(part, off, 64);
    if (lane == 0) fb[o] = part + bproj[o];
    return;
  }

  __shared__ ushort_t As[128 * 64];    // [o-row][64k], (r&7) chunk-XOR
  __shared__ ushort_t Bs[128 * 64];    // [c-row][64k], kkey(c) chunk-XOR
  int c0 = (bid & 3) * 128;
  int o0 = (bid >> 2) * 128;
  int wave = tid >> 6, lane = tid & 63;
  int wo = (wave & 1) * 64, wp = (wave >> 1) * 64;
  int q = lane >> 4, ln = lane & 15;

  f32x4 zero = {0.f, 0.f, 0.f, 0.f};
  f32x4 acc[4][4];
#pragma unroll
  for (int i = 0; i < 4; ++i)
#pragma unroll
    for (int j = 0; j < 4; ++j) acc[i][j] = zero;

  int sr = tid >> 3;                   // A staging: row 0..31 per sweep
  int sc = tid & 7;                    // 16B chunk 0..7
  const float* Ag = wproj + (long)(o0 + sr) * DIMC + sc * 8;
  int kr = tid >> 5;                   // B staging: k-row 0..7 per pass
  int c4 = (tid & 31) * 4;             // 4 c per thread

  for (int kc = 0; kc < DIMC; kc += 64) {
    __syncthreads();
    // A: cast f32 -> bf16
#pragma unroll
    for (int it = 0; it < 4; ++it) {
      int r = sr + it * 32;
      float4 a0 = *(const float4*)(Ag + (long)it * 32 * DIMC + kc);
      float4 a1 = *(const float4*)(Ag + (long)it * 32 * DIMC + kc + 4);
      *(uint4*)(&As[r * 64 + ((sc ^ (r & 7)) * 8)]) = pack8(a0, a1);
    }
    // B: transpose+cast from wqkv V-block rows (coalesced f32 reads along c)
#pragma unroll
    for (int ps = 0; ps < 8; ++ps) {
      int k = kc + ps * 8 + kr;        // global k' in [kc, kc+64)
      float4 b = *(const float4*)(wqkv + (long)(1024 + k) * DIMC + c0 + c4);
      char* bsb = (char*)Bs;
      ushort_t e[4] = {f2bf(b.x), f2bf(b.y), f2bf(b.z), f2bf(b.w)};
#pragma unroll
      for (int i = 0; i < 4; ++i) {
        int c = c4 + i;
        *(ushort_t*)(bsb + c * 128 + ((ps ^ kkey(c)) * 16) + kr * 2) = e[i];
      }
    }
    __syncthreads();
#pragma unroll
    for (int ks = 0; ks < 2; ++ks) {
      int cch = ks * 4 + q;
      short8 af[4], bf[4];
#pragma unroll
      for (int mi = 0; mi < 4; ++mi) {
        int row = wo + mi * 16 + ln;
        af[mi] = *(const short8*)(&As[row * 64 + ((cch ^ (row & 7)) * 8)]);
      }
#pragma unroll
      for (int ni = 0; ni < 4; ++ni) {
        int row = wp + ni * 16 + ln;
        bf[ni] = *(const short8*)(&Bs[row * 64 + ((cch ^ kkey(row)) * 8)]);
      }
#pragma unroll
      for (int mi = 0; mi < 4; ++mi)
#pragma unroll
        for (int ni = 0; ni < 4; ++ni)
          acc[mi][ni] = __builtin_amdgcn_mfma_f32_16x16x32_bf16(af[mi], bf[ni], acc[mi][ni], 0, 0, 0);
    }
  }

#pragma unroll
  for (int mi = 0; mi < 4; ++mi) {
    int obase = o0 + wo + mi * 16 + q * 4;
#pragma unroll
    for (int ni = 0; ni < 4; ++ni) {
      int c = c0 + wp + ni * 16 + ln;
      float g = gamma[c];
      int kb2 = c >> 6, ks2 = (c >> 5) & 1, q2 = (c >> 3) & 3, j2 = c & 7;
#pragma unroll
      for (int r = 0; r < 4; ++r) {
        int o = obase + r;
        int w2 = o >> 6, mi2 = (o >> 4) & 3, ln2 = o & 15;
        long idx = (((((long)w2 * 8 + kb2) * 2 + ks2) * 4 + mi2) * 64 + q2 * 16 + ln2) * 8 + j2;
        Mp2[idx] = f2bf(acc[mi][ni][r] * g);
      }
    }
  }
}

// ---------------- fused transpose + RMS + GEMM + reg-resident residual,
// TWO-TILE cross-pipelined. Grid 256 (1 block/CU), block owns p-tiles
// {2b, 2b+1}. Tile-1's 16 x-loads are issued right after GEMM(t0) and
// complete under EPI(t0)'s ~10us NT-store stream (T14 issue-early).
// Epilogue reads NOTHING from global (identity in regs, acc via LDS
// transpose) -> no R9-style L2 thrash; NT float4 stores keep write-merge.
__global__ __launch_bounds__(512, 2) void k_fused(
    const float* __restrict__ x,
    const ushort_t* __restrict__ Mp2,  // fragment layout, 512KB (L2/L3-hot)
    const float* __restrict__ fb,
    float* __restrict__ out) {
  __shared__ __align__(16) char smem[80512];
  ushort_t* xs = (ushort_t*)smem;              // [8][64][64] staging (65536 B)
  float* ot    = (float*)smem;                 // [256][68] acc transpose (69632 B, reuses xs)
  float* red   = (float*)(smem + 69632);       // [32][65] (8320 B)
  float* s_sh  = (float*)(smem + 77952);       // [2][64]
  float* fb_sh = (float*)(smem + 78464);       // [512]
  int tid = threadIdx.x;
  long pt0 = (long)blockIdx.x * 128;           // grid 256; tiles at pt0, pt0+64

  int wave = tid >> 6, lane = tid & 63;
  int q = lane >> 4, ln = lane & 15;
  int pl4 = (tid & 15) * 4;                    // p-group base 0,4,..,60
  int kq  = tid >> 4;                          // 0..31

  const ushort_t* Aw = Mp2 + (long)wave * 32768 + lane * 8;

  fb_sh[tid] = fb[tid];                        // 512 f32, coalesced

  float4 va[16], vb[16];
  f32x4 acc[4][4];
  short8 afb[2][8];
  f32x4 zero = {0.f, 0.f, 0.f, 0.f};

#define LOADV(V, TB)                                                     \
  {                                                                      \
    _Pragma("unroll")                                                    \
    for (int sw = 0; sw < 4; ++sw) {                                     \
      const float* xp = x + (long)(kq * 4 + sw * 128) * PN + (TB) + pl4; \
      _Pragma("unroll")                                                  \
      for (int j = 0; j < 4; ++j)                                        \
        V[sw * 4 + j] = *(const float4*)(xp + (long)j * PN);             \
    }                                                                    \
  }

#define PREFA()                                                          \
  {                                                                      \
    _Pragma("unroll")                                                    \
    for (int f = 0; f < 8; ++f) afb[0][f] = *(const short8*)(Aw + f * 512); \
  }

#define PROCESSV(V)                                                                    \
  {                                                                                    \
    float ss0 = 0.f, ss1 = 0.f, ss2 = 0.f, ss3 = 0.f;                                  \
    _Pragma("unroll")                                                                  \
    for (int sw = 0; sw < 4; ++sw) {                                                   \
      int k4 = kq * 4 + sw * 128;                                                      \
      float4 v0 = V[sw * 4 + 0], v1 = V[sw * 4 + 1];                                   \
      float4 v2 = V[sw * 4 + 2], v3 = V[sw * 4 + 3];                                   \
      ss0 += v0.x * v0.x + v1.x * v1.x + v2.x * v2.x + v3.x * v3.x;                    \
      ss1 += v0.y * v0.y + v1.y * v1.y + v2.y * v2.y + v3.y * v3.y;                    \
      ss2 += v0.z * v0.z + v1.z * v1.z + v2.z * v2.z + v3.z * v3.z;                    \
      ss3 += v0.w * v0.w + v1.w * v1.w + v2.w * v2.w + v3.w * v3.w;                    \
      ushort_t t0[4] = {f2bf(v0.x), f2bf(v1.x), f2bf(v2.x), f2bf(v3.x)};               \
      ushort_t t1[4] = {f2bf(v0.y), f2bf(v1.y), f2bf(v2.y), f2bf(v3.y)};               \
      ushort_t t2[4] = {f2bf(v0.z), f2bf(v1.z), f2bf(v2.z), f2bf(v3.z)};               \
      ushort_t t3[4] = {f2bf(v0.w), f2bf(v1.w), f2bf(v2.w), f2bf(v3.w)};               \
      char* base = (char*)xs + (k4 >> 6) * 8192;                                       \
      int ch  = (k4 >> 3) & 7;                                                         \
      int sub = (k4 & 7) * 2;                                                          \
      *(uint2*)(base + (pl4 + 0) * 128 + ((ch ^ kkey(pl4 + 0)) * 16) + sub) = *(const uint2*)t0; \
      *(uint2*)(base + (pl4 + 1) * 128 + ((ch ^ kkey(pl4 + 1)) * 16) + sub) = *(const uint2*)t1; \
      *(uint2*)(base + (pl4 + 2) * 128 + ((ch ^ kkey(pl4 + 2)) * 16) + sub) = *(const uint2*)t2; \
      *(uint2*)(base + (pl4 + 3) * 128 + ((ch ^ kkey(pl4 + 3)) * 16) + sub) = *(const uint2*)t3; \
    }                                                                                  \
    red[kq * 65 + pl4 + 0] = ss0;                                                      \
    red[kq * 65 + pl4 + 1] = ss1;                                                      \
    red[kq * 65 + pl4 + 2] = ss2;                                                      \
    red[kq * 65 + pl4 + 3] = ss3;                                                      \
  }

#define SREDUCE(SI)                                          \
  if (tid < 64) {                                            \
    float t = 0.f;                                           \
    _Pragma("unroll")                                        \
    for (int g = 0; g < 32; ++g) t += red[g * 65 + tid];     \
    s_sh[(SI) * 64 + tid] = SQRTC / fmaxf(sqrtf(t), 1e-12f); \
  }

#define GEMMT()                                                                   \
  {                                                                               \
    _Pragma("unroll")                                                             \
    for (int i = 0; i < 4; ++i)                                                   \
      _Pragma("unroll")                                                           \
      for (int j = 0; j < 4; ++j) acc[i][j] = zero;                               \
    _Pragma("unroll")                                                             \
    for (int kb = 0; kb < 8; ++kb) {                                              \
      if (kb < 7) {                                                               \
        _Pragma("unroll")                                                         \
        for (int f = 0; f < 8; ++f)                                               \
          afb[(kb + 1) & 1][f] = *(const short8*)(Aw + ((kb + 1) * 8 + f) * 512); \
      }                                                                           \
      const char* bbase = (const char*)xs + kb * 8192;                            \
      _Pragma("unroll")                                                           \
      for (int ks = 0; ks < 2; ++ks) {                                            \
        int cch = ks * 4 + q;                                                     \
        short8 bfr[4];                                                            \
        _Pragma("unroll")                                                         \
        for (int ni = 0; ni < 4; ++ni) {                                          \
          int row = ni * 16 + ln;                                                 \
          bfr[ni] = *(const short8*)(bbase + row * 128 + ((cch ^ kkey(row)) * 16)); \
        }                                                                         \
        _Pragma("unroll")                                                         \
        for (int mi = 0; mi < 4; ++mi)                                            \
          _Pragma("unroll")                                                       \
          for (int ni = 0; ni < 4; ++ni)                                          \
            acc[mi][ni] = __builtin_amdgcn_mfma_f32_16x16x32_bf16(                \
                afb[kb & 1][ks * 4 + mi], bfr[ni], acc[mi][ni], 0, 0, 0);         \
      }                                                                           \
    }                                                                             \
  }

#define EPI(V, TB, SI)                                                            \
  {                                                                               \
    int ccmy = (kq >> 3) & 1;                                                     \
    float s4x = s_sh[(SI) * 64 + pl4 + 0], s4y = s_sh[(SI) * 64 + pl4 + 1];       \
    float s4z = s_sh[(SI) * 64 + pl4 + 2], s4w = s_sh[(SI) * 64 + pl4 + 3];       \
    _Pragma("unroll")                                                             \
    for (int cc = 0; cc < 2; ++cc) {                                              \
      _Pragma("unroll")                                                           \
      for (int mm = 0; mm < 2; ++mm) {                                            \
        int mi = cc * 2 + mm;                                                     \
        int rbase = wave * 32 + mm * 16 + q * 4;                                  \
        _Pragma("unroll")                                                         \
        for (int ni = 0; ni < 4; ++ni)                                            \
          _Pragma("unroll")                                                       \
          for (int r = 0; r < 4; ++r)                                             \
            ot[(rbase + r) * 68 + ni * 16 + ln] = acc[mi][ni][r];                 \
      }                                                                           \
      __syncthreads();                                                            \
      if (ccmy == cc) {                                                           \
        _Pragma("unroll")                                                         \
        for (int sw = 0; sw < 4; ++sw)                                            \
          _Pragma("unroll")                                                       \
          for (int j = 0; j < 4; ++j) {                                           \
            int o = kq * 4 + sw * 128 + j;                                        \
            int r_loc = (o >> 6) * 32 + (o & 31);                                 \
            const float* gp = ot + r_loc * 68 + pl4;                              \
            float fbv = fb_sh[o];                                                 \
            float4 xv = V[sw * 4 + j];                                            \
            f32x4 res;                                                            \
            res[0] = xv.x + fbv + s4x * gp[0];                                    \
            res[1] = xv.y + fbv + s4y * gp[1];                                    \
            res[2] = xv.z + fbv + s4z * gp[2];                                    \
            res[3] = xv.w + fbv + s4w * gp[3];                                    \
            __builtin_nontemporal_store(res, (f32x4*)(out + (long)o * PN + (TB) + pl4)); \
          }                                                                       \
      }                                                                           \
      if (cc == 0) __syncthreads();                                               \
    }                                                                             \
  }

  // ================= tile 0 =================
  LOADV(va, pt0);
  PREFA();                          // kb0 A-frags in flight during staging
  PROCESSV(va);
  __syncthreads();                  // xs(t0) + red + fb_sh published
  SREDUCE(0);
  GEMMT();                          // acc = t0
  __syncthreads();                  // xs reads done; s_sh[0] visible

  // ====== pipeline point: t1 loads fly under EPI(t0)'s store stream ======
  LOADV(vb, pt0 + 64);
  EPI(va, pt0, 0);
  __syncthreads();                  // ot reads done before xs(t1) overwrite
  PREFA();                          // t1 kb0 A-frags under processing
  PROCESSV(vb);
  __syncthreads();                  // xs(t1) + red published
  SREDUCE(1);

  // ================= tile 1 =================
  GEMMT();                          // acc = t1
  __syncthreads();                  // s_sh[1] visible
  EPI(vb, pt0 + 64, 1);

#undef LOADV
#undef PREFA
#undef PROCESSV
#undef SREDUCE
#undef GEMMT
#undef EPI
}

extern "C" void kernel_launch(void* const* d_in, const int* in_sizes, int n_in,
                              void* d_out, int out_size, void* d_ws, size_t ws_size,
                              hipStream_t stream) {
  const float* x     = (const float*)d_in[0];
  const float* gamma = (const float*)d_in[1];
  const float* wqkv  = (const float*)d_in[2];
  const float* bqkv  = (const float*)d_in[3];
  const float* wproj = (const float*)d_in[4];
  const float* bproj = (const float*)d_in[5];

  char* ws = (char*)d_ws;
  ushort_t* Mp2 = (ushort_t*)(ws);             // 512*512 bf16 fragment layout (524288 B)
  float*    fb  = (float*)(ws + 524288);       // 512 f32

  // Mp2(frag) = (wproj @ V-weight^T) * gamma, fb = wproj@bqkv_v + bproj
  k_wgemm<<<dim3(144), dim3(256), 0, stream>>>(wproj, wqkv, bqkv, bproj, gamma, Mp2, fb);
  // out[o][p] = x[o][p] + fb[o] + s[p] * sum_c Mp[o,c]*bf16(x[c,p])
  k_fused<<<dim3(256), dim3(512), 0, stream>>>(x, Mp2, fb, (float*)d_out);
}

// Round 13
// 152.566 us; speedup vs baseline: 1.1875x; 1.1875x over previous
//
#include <hip/hip_runtime.h>

typedef unsigned short ushort_t;
typedef __attribute__((ext_vector_type(8))) short short8;
typedef __attribute__((ext_vector_type(4))) float f32x4;

#define DIMC 512
#define PN   32768                  // 8*64*64 spatial positions
#define SQRTC 22.627416997969522f   // sqrt(512)

__device__ __forceinline__ ushort_t f2bf(float f) {
  unsigned int u = __float_as_uint(f);
  unsigned int r = u + 0x7fffu + ((u >> 16) & 1u);   // round-to-nearest-even
  return (ushort_t)(r >> 16);
}

// swizzle key: spreads 8 values over 16 consecutive rows AND over stride-4 rows
__device__ __forceinline__ int kkey(int r) { return (r & 7) ^ ((r >> 2) & 7); }

__device__ __forceinline__ uint4 pack8(float4 a, float4 b) {
  union { ushort_t u[8]; uint4 v; } r;
  r.u[0] = f2bf(a.x); r.u[1] = f2bf(a.y); r.u[2] = f2bf(a.z); r.u[3] = f2bf(a.w);
  r.u[4] = f2bf(b.x); r.u[5] = f2bf(b.y); r.u[6] = f2bf(b.z); r.u[7] = f2bf(b.w);
  return r.v;
}

// ---------------- weight GEMM with fused cast+transpose staging + fb (2-in-1):
// blocks 0..15:   Mp2(frag layout) = (wproj @ Wv^T) * gamma
// blocks 16..143: fb[o] = wproj[o,:]·bqkv[1024:1536] + bproj[o]
// Mp2 layout: idx(o,c) = ((((w*8+kb)*2+ks)*4+mi)*64 + q*16+ln)*8 + j
//   w=o>>6, mi=(o>>4)&3, ln=o&15, kb=c>>6, ks=(c>>5)&1, q=(c>>3)&3, j=c&7
__global__ __launch_bounds__(256) void k_wgemm(
    const float* __restrict__ wproj,
    const float* __restrict__ wqkv,
    const float* __restrict__ bqkv,
    const float* __restrict__ bproj,
    const float* __restrict__ gamma,
    ushort_t* __restrict__ Mp2,
    float* __restrict__ fb) {
  int bid = blockIdx.x, tid = threadIdx.x;
  if (bid >= 16) {
    int wave = tid >> 6, lane = tid & 63;
    int o = (bid - 16) * 4 + wave;          // 128 blocks -> o in [0,512)
    float part = 0.f;
#pragma unroll
    for (int i = 0; i < 8; ++i) {
      int k = lane + i * 64;
      part += wproj[o * DIMC + k] * bqkv[1024 + k];
    }
    for (int off = 32; off; off >>= 1) part += __shfl_down(part, off, 64);
    if (lane == 0) fb[o] = part + bproj[o];
    return;
  }

  __shared__ ushort_t As[128 * 64];    // [o-row][64k], (r&7) chunk-XOR
  __shared__ ushort_t Bs[128 * 64];    // [c-row][64k], kkey(c) chunk-XOR
  int c0 = (bid & 3) * 128;
  int o0 = (bid >> 2) * 128;
  int wave = tid >> 6, lane = tid & 63;
  int wo = (wave & 1) * 64, wp = (wave >> 1) * 64;
  int q = lane >> 4, ln = lane & 15;

  f32x4 zero = {0.f, 0.f, 0.f, 0.f};
  f32x4 acc[4][4];
#pragma unroll
  for (int i = 0; i < 4; ++i)
#pragma unroll
    for (int j = 0; j < 4; ++j) acc[i][j] = zero;

  int sr = tid >> 3;                   // A staging: row 0..31 per sweep
  int sc = tid & 7;                    // 16B chunk 0..7
  const float* Ag = wproj + (long)(o0 + sr) * DIMC + sc * 8;
  int kr = tid >> 5;                   // B staging: k-row 0..7 per pass
  int c4 = (tid & 31) * 4;             // 4 c per thread

  for (int kc = 0; kc < DIMC; kc += 64) {
    __syncthreads();
    // A: cast f32 -> bf16
#pragma unroll
    for (int it = 0; it < 4; ++it) {
      int r = sr + it * 32;
      float4 a0 = *(const float4*)(Ag + (long)it * 32 * DIMC + kc);
      float4 a1 = *(const float4*)(Ag + (long)it * 32 * DIMC + kc + 4);
      *(uint4*)(&As[r * 64 + ((sc ^ (r & 7)) * 8)]) = pack8(a0, a1);
    }
    // B: transpose+cast from wqkv V-block rows (coalesced f32 reads along c)
#pragma unroll
    for (int ps = 0; ps < 8; ++ps) {
      int k = kc + ps * 8 + kr;        // global k' in [kc, kc+64)
      float4 b = *(const float4*)(wqkv + (long)(1024 + k) * DIMC + c0 + c4);
      char* bsb = (char*)Bs;
      ushort_t e[4] = {f2bf(b.x), f2bf(b.y), f2bf(b.z), f2bf(b.w)};
#pragma unroll
      for (int i = 0; i < 4; ++i) {
        int c = c4 + i;
        *(ushort_t*)(bsb + c * 128 + ((ps ^ kkey(c)) * 16) + kr * 2) = e[i];
      }
    }
    __syncthreads();
#pragma unroll
    for (int ks = 0; ks < 2; ++ks) {
      int cch = ks * 4 + q;
      short8 af[4], bf[4];
#pragma unroll
      for (int mi = 0; mi < 4; ++mi) {
        int row = wo + mi * 16 + ln;
        af[mi] = *(const short8*)(&As[row * 64 + ((cch ^ (row & 7)) * 8)]);
      }
#pragma unroll
      for (int ni = 0; ni < 4; ++ni) {
        int row = wp + ni * 16 + ln;
        bf[ni] = *(const short8*)(&Bs[row * 64 + ((cch ^ kkey(row)) * 8)]);
      }
#pragma unroll
      for (int mi = 0; mi < 4; ++mi)
#pragma unroll
        for (int ni = 0; ni < 4; ++ni)
          acc[mi][ni] = __builtin_amdgcn_mfma_f32_16x16x32_bf16(af[mi], bf[ni], acc[mi][ni], 0, 0, 0);
    }
  }

#pragma unroll
  for (int mi = 0; mi < 4; ++mi) {
    int obase = o0 + wo + mi * 16 + q * 4;
#pragma unroll
    for (int ni = 0; ni < 4; ++ni) {
      int c = c0 + wp + ni * 16 + ln;
      float g = gamma[c];
      int kb2 = c >> 6, ks2 = (c >> 5) & 1, q2 = (c >> 3) & 3, j2 = c & 7;
#pragma unroll
      for (int r = 0; r < 4; ++r) {
        int o = obase + r;
        int w2 = o >> 6, mi2 = (o >> 4) & 3, ln2 = o & 15;
        long idx = (((((long)w2 * 8 + kb2) * 2 + ks2) * 4 + mi2) * 64 + q2 * 16 + ln2) * 8 + j2;
        Mp2[idx] = f2bf(acc[mi][ni][r] * g);
      }
    }
  }
}

// ---------------- fused transpose + RMS + GEMM + register-resident residual,
// K-SPLIT pipelined (R11 geometry, proven 47.5us, + one change):
// stage k[0,256) -> barrier -> ISSUE k[256,512) loads -> GEMM kb0-3 under
// them -> process half B -> barrier -> GEMM kb4-7 -> R11 epilogue.
// Loads overlap only MFMA/VALU, never the NT-store stream (R9/R12 lesson).
__global__ __launch_bounds__(512, 2) void k_fused(
    const float* __restrict__ x,
    const ushort_t* __restrict__ Mp2,  // fragment layout, 512KB (L2/L3-hot)
    const float* __restrict__ fb,
    float* __restrict__ out) {
  __shared__ __align__(16) char smem[80256];
  ushort_t* xs = (ushort_t*)smem;              // [8][64][64] staging (65536 B)
  float* ot    = (float*)smem;                 // [256][68] acc transpose (69632 B, reuses xs)
  float* red   = (float*)(smem + 69632);       // [32][65] (8320 B)
  float* s_sh  = (float*)(smem + 77952);       // [64]
  float* fb_sh = (float*)(smem + 78208);       // [512]
  int tid = threadIdx.x;
  long p0 = (long)blockIdx.x * 64;             // grid 512

  int wave = tid >> 6, lane = tid & 63;
  int q = lane >> 4, ln = lane & 15;
  int pl4 = (tid & 15) * 4;                    // p-group base 0,4,..,60
  int kq  = tid >> 4;                          // 0..31

  const ushort_t* Aw = Mp2 + (long)wave * 32768 + lane * 8;

  fb_sh[tid] = fb[tid];                        // 512 f32, coalesced

  float4 v[16];
  float ss0 = 0.f, ss1 = 0.f, ss2 = 0.f, ss3 = 0.f;
  f32x4 zero = {0.f, 0.f, 0.f, 0.f};
  f32x4 acc[4][4];
  short8 afb[2][8];

#define LOADH(S0)                                                        \
  {                                                                      \
    _Pragma("unroll")                                                    \
    for (int sw = (S0); sw < (S0) + 2; ++sw) {                           \
      const float* xp = x + (long)(kq * 4 + sw * 128) * PN + p0 + pl4;   \
      _Pragma("unroll")                                                  \
      for (int j = 0; j < 4; ++j)                                        \
        v[sw * 4 + j] = *(const float4*)(xp + (long)j * PN);             \
    }                                                                    \
  }

#define PROCH(S0)                                                                      \
  {                                                                                    \
    _Pragma("unroll")                                                                  \
    for (int sw = (S0); sw < (S0) + 2; ++sw) {                                         \
      int k4 = kq * 4 + sw * 128;                                                      \
      float4 v0 = v[sw * 4 + 0], v1 = v[sw * 4 + 1];                                   \
      float4 v2 = v[sw * 4 + 2], v3 = v[sw * 4 + 3];                                   \
      ss0 += v0.x * v0.x + v1.x * v1.x + v2.x * v2.x + v3.x * v3.x;                    \
      ss1 += v0.y * v0.y + v1.y * v1.y + v2.y * v2.y + v3.y * v3.y;                    \
      ss2 += v0.z * v0.z + v1.z * v1.z + v2.z * v2.z + v3.z * v3.z;                    \
      ss3 += v0.w * v0.w + v1.w * v1.w + v2.w * v2.w + v3.w * v3.w;                    \
      ushort_t t0[4] = {f2bf(v0.x), f2bf(v1.x), f2bf(v2.x), f2bf(v3.x)};               \
      ushort_t t1[4] = {f2bf(v0.y), f2bf(v1.y), f2bf(v2.y), f2bf(v3.y)};               \
      ushort_t t2[4] = {f2bf(v0.z), f2bf(v1.z), f2bf(v2.z), f2bf(v3.z)};               \
      ushort_t t3[4] = {f2bf(v0.w), f2bf(v1.w), f2bf(v2.w), f2bf(v3.w)};               \
      char* base = (char*)xs + (k4 >> 6) * 8192;                                       \
      int ch  = (k4 >> 3) & 7;                                                         \
      int sub = (k4 & 7) * 2;                                                          \
      *(uint2*)(base + (pl4 + 0) * 128 + ((ch ^ kkey(pl4 + 0)) * 16) + sub) = *(const uint2*)t0; \
      *(uint2*)(base + (pl4 + 1) * 128 + ((ch ^ kkey(pl4 + 1)) * 16) + sub) = *(const uint2*)t1; \
      *(uint2*)(base + (pl4 + 2) * 128 + ((ch ^ kkey(pl4 + 2)) * 16) + sub) = *(const uint2*)t2; \
      *(uint2*)(base + (pl4 + 3) * 128 + ((ch ^ kkey(pl4 + 3)) * 16) + sub) = *(const uint2*)t3; \
    }                                                                                  \
  }

#define GEMMR(KB0, KB1)                                                          \
  {                                                                              \
    _Pragma("unroll")                                                            \
    for (int kb = (KB0); kb < (KB1); ++kb) {                                     \
      if (kb < 7) {                                                              \
        _Pragma("unroll")                                                        \
        for (int f = 0; f < 8; ++f)                                              \
          afb[(kb + 1) & 1][f] = *(const short8*)(Aw + ((kb + 1) * 8 + f) * 512); \
      }                                                                          \
      const char* bbase = (const char*)xs + kb * 8192;                           \
      _Pragma("unroll")                                                          \
      for (int ks = 0; ks < 2; ++ks) {                                           \
        int cch = ks * 4 + q;                                                    \
        short8 bfr[4];                                                           \
        _Pragma("unroll")                                                        \
        for (int ni = 0; ni < 4; ++ni) {                                         \
          int row = ni * 16 + ln;                                                \
          bfr[ni] = *(const short8*)(bbase + row * 128 + ((cch ^ kkey(row)) * 16)); \
        }                                                                        \
        _Pragma("unroll")                                                        \
        for (int mi = 0; mi < 4; ++mi)                                           \
          _Pragma("unroll")                                                      \
          for (int ni = 0; ni < 4; ++ni)                                         \
            acc[mi][ni] = __builtin_amdgcn_mfma_f32_16x16x32_bf16(               \
                afb[kb & 1][ks * 4 + mi], bfr[ni], acc[mi][ni], 0, 0, 0);        \
      }                                                                          \
    }                                                                            \
  }

  // ---- half A: stage k[0,256)  (kb 0..3)
  LOADH(0);
  // kb0 A-fragments issued while x-loads are in flight
#pragma unroll
  for (int f = 0; f < 8; ++f) afb[0][f] = *(const short8*)(Aw + f * 512);
  PROCH(0);
  __syncthreads();                             // xs kb0-3 + fb_sh published

  // ---- pipeline: half-B loads fly under GEMM kb0-3
  LOADH(2);
#pragma unroll
  for (int i = 0; i < 4; ++i)
#pragma unroll
    for (int j = 0; j < 4; ++j) acc[i][j] = zero;
  GEMMR(0, 4);
  PROCH(2);                                    // vmcnt waits land after MFMAs
  red[kq * 65 + pl4 + 0] = ss0;
  red[kq * 65 + pl4 + 1] = ss1;
  red[kq * 65 + pl4 + 2] = ss2;
  red[kq * 65 + pl4 + 3] = ss3;
  __syncthreads();                             // xs kb4-7 + red published

  // ---- wave 0 reduces s while other waves run GEMM kb4-7
  if (tid < 64) {
    float t = 0.f;
#pragma unroll
    for (int g = 0; g < 32; ++g) t += red[g * 65 + tid];
    s_sh[tid] = SQRTC / fmaxf(sqrtf(t), 1e-12f);
  }
  GEMMR(4, 8);
  __syncthreads();                             // GEMM reads of xs done; s_sh ready

  // ---- epilogue: acc -> LDS transpose (2 chunks), combine with reg-held v.
  int ccmy = (kq >> 3) & 1;
  float s4x = s_sh[pl4 + 0], s4y = s_sh[pl4 + 1];
  float s4z = s_sh[pl4 + 2], s4w = s_sh[pl4 + 3];
#pragma unroll
  for (int cc = 0; cc < 2; ++cc) {
#pragma unroll
    for (int mm = 0; mm < 2; ++mm) {
      int mi = cc * 2 + mm;
      int rbase = wave * 32 + mm * 16 + q * 4;
#pragma unroll
      for (int ni = 0; ni < 4; ++ni)
#pragma unroll
        for (int r = 0; r < 4; ++r)
          ot[(rbase + r) * 68 + ni * 16 + ln] = acc[mi][ni][r];
    }
    __syncthreads();                           // ot(chunk cc) published
    if (ccmy == cc) {
#pragma unroll
      for (int sw = 0; sw < 4; ++sw)
#pragma unroll
        for (int j = 0; j < 4; ++j) {
          int o = kq * 4 + sw * 128 + j;
          int r_loc = (o >> 6) * 32 + (o & 31);
          const float* gp = ot + r_loc * 68 + pl4;
          float fbv = fb_sh[o];
          float4 xv = v[sw * 4 + j];
          f32x4 res;
          res[0] = xv.x + fbv + s4x * gp[0];
          res[1] = xv.y + fbv + s4y * gp[1];
          res[2] = xv.z + fbv + s4z * gp[2];
          res[3] = xv.w + fbv + s4w * gp[3];
          __builtin_nontemporal_store(res, (f32x4*)(out + (long)o * PN + p0 + pl4));
        }
    }
    if (cc == 0) __syncthreads();              // protect ot before chunk-1 writes
  }
#undef LOADH
#undef PROCH
#undef GEMMR
}

extern "C" void kernel_launch(void* const* d_in, const int* in_sizes, int n_in,
                              void* d_out, int out_size, void* d_ws, size_t ws_size,
                              hipStream_t stream) {
  const float* x     = (const float*)d_in[0];
  const float* gamma = (const float*)d_in[1];
  const float* wqkv  = (const float*)d_in[2];
  const float* bqkv  = (const float*)d_in[3];
  const float* wproj = (const float*)d_in[4];
  const float* bproj = (const float*)d_in[5];

  char* ws = (char*)d_ws;
  ushort_t* Mp2 = (ushort_t*)(ws);             // 512*512 bf16 fragment layout (524288 B)
  float*    fb  = (float*)(ws + 524288);       // 512 f32

  // Mp2(frag) = (wproj @ V-weight^T) * gamma, fb = wproj@bqkv_v + bproj
  k_wgemm<<<dim3(144), dim3(256), 0, stream>>>(wproj, wqkv, bqkv, bproj, gamma, Mp2, fb);
  // out[o][p] = x[o][p] + fb[o] + s[p] * sum_c Mp[o,c]*bf16(x[c,p])
  k_fused<<<dim3(512), dim3(512), 0, stream>>>(x, Mp2, fb, (float*)d_out);
}